// Round 1
// baseline (306.217 us; speedup 1.0000x reference)
//
#include <hip/hip_runtime.h>
#include <stdint.h>
#include <stddef.h>

// MASLoRALinear: out[b,t,o] = x@W_base^T + b_base + SCALING * sum_e w[b,e] * (x@A_e^T)@B_e^T
// Folded: per-batch merged weight W_m[b] = W_base + SCALING * sum_e w[b,e] * (B_e @ A_e)
// then one batched bf16-MFMA GEMM: out[b] = x[b] @ W_m[b]^T + b_base.
// Dims fixed by the problem: B=16, T=1500, C=1024, O=1024, E=8, R=16, SCALING=2.

#define B_ 16
#define T_ 1500
#define C_ 1024
#define O_ 1024
#define E_ 8
#define R_ 16
#define SCALING 2.0f

typedef __bf16 bf16x8 __attribute__((ext_vector_type(8)));
typedef float f32x4 __attribute__((ext_vector_type(4)));
typedef unsigned short u16;

__device__ inline u16 f2bf(float f) {
  union { float f; unsigned u; } v; v.f = f;
  unsigned u = v.u;
  u += 0x7fff + ((u >> 16) & 1);   // round-to-nearest-even
  return (u16)(u >> 16);
}

// ---------------- kernel 1: x fp32 -> bf16 (ws) ----------------
// 24,576,000 elements / 4 per thread = 6,144,000 threads = 24000 blocks x 256.
__global__ __launch_bounds__(256) void cvt_x(const float4* __restrict__ x,
                                             ushort4* __restrict__ xb) {
  int i = blockIdx.x * 256 + threadIdx.x;
  float4 v = x[i];
  ushort4 o;
  o.x = f2bf(v.x); o.y = f2bf(v.y); o.z = f2bf(v.z); o.w = f2bf(v.w);
  xb[i] = o;
}

// ---------------- kernel 2: build merged weights (bf16, ws) ----------------
// wm[b][o][c] = W_base[o][c] + SCALING * sum_e w[b,e] * sum_r Bs[e,o,r]*As[e,r,c]
// grid: O_*C_/256 = 4096 blocks; each wave shares one o (1024 c's per o, 256 | 1024)
// so Bs reads are wave-uniform (scalar), As reads coalesced (As is 512 KB -> L2).
__global__ __launch_bounds__(256) void build_wm(const float* __restrict__ w,
                                                const float* __restrict__ Wb,
                                                const float* __restrict__ As,
                                                const float* __restrict__ Bs,
                                                u16* __restrict__ wm) {
  int idx = blockIdx.x * 256 + threadIdx.x;  // o*1024 + c
  int o = idx >> 10;
  int c = idx & 1023;
  float d[E_];
#pragma unroll
  for (int e = 0; e < E_; ++e) {
    float acc = 0.f;
#pragma unroll
    for (int r = 0; r < R_; ++r)
      acc += Bs[(e * O_ + o) * R_ + r] * As[(e * R_ + r) * C_ + c];
    d[e] = acc;
  }
  float base = Wb[idx];
#pragma unroll
  for (int b = 0; b < B_; ++b) {
    float s = 0.f;
#pragma unroll
    for (int e = 0; e < E_; ++e) s += w[b * E_ + e] * d[e];
    wm[(size_t)b * (O_ * C_) + idx] = f2bf(base + SCALING * s);
  }
}

// ---------------- kernel 3: batched GEMM (m97 structure) ----------------
// out[b][m][n] = sum_k xb[b][m][k] * wm[b][n][k] + b_base[n]
// 128x128 tile, BK=32, 4 waves, each wave 4x4 grid of 16x16x32 bf16 MFMA.
// Staging via global_load_lds width=16 (2 chunks per operand per thread per K-step).
__global__ __launch_bounds__(256) void gemm_merged(const u16* __restrict__ xb,
                                                   const u16* __restrict__ wm,
                                                   const float* __restrict__ bbase,
                                                   float* __restrict__ out) {
  const int mt = blockIdx.x;   // 0..11 (tail tile partial: 1500 = 11*128 + 92)
  const int nt = blockIdx.y;   // 0..7
  const int b = blockIdx.z;    // 0..15
  const int tid = threadIdx.x;
  const int lane = tid & 63;
  const int wv = tid >> 6;
  const int wrow = wv & 1;     // wave m-half
  const int wcol = wv >> 1;    // wave n-half
  const int l15 = lane & 15;
  const int quad = lane >> 4;

  __shared__ u16 lA[128 * 32];
  __shared__ u16 lB[128 * 32];

  const u16* gA = xb + ((size_t)b * T_ + (size_t)mt * 128) * C_;
  const u16* gB = wm + ((size_t)b * O_ + (size_t)nt * 128) * C_;

  f32x4 acc[4][4];
#pragma unroll
  for (int i = 0; i < 4; ++i)
#pragma unroll
    for (int j = 0; j < 4; ++j) acc[i][j] = (f32x4){0.f, 0.f, 0.f, 0.f};

  // staging map: chunk idx in [0,512): row = idx>>2 (128 rows), kchunk = idx&3 (4 x 8 bf16)
  const int idx0 = tid;
  const int idx1 = 256 + tid;
  const int r0 = idx0 >> 2, kc0 = idx0 & 3;
  const int r1 = idx1 >> 2, kc1 = idx1 & 3;

  for (int kt = 0; kt < C_ / 32; ++kt) {
    const int k0 = kt * 32;
    __builtin_amdgcn_global_load_lds(
        (const __attribute__((address_space(1))) void*)(gA + (size_t)r0 * C_ + k0 + kc0 * 8),
        (__attribute__((address_space(3))) void*)(&lA[idx0 * 8]), 16, 0, 0);
    __builtin_amdgcn_global_load_lds(
        (const __attribute__((address_space(1))) void*)(gA + (size_t)r1 * C_ + k0 + kc1 * 8),
        (__attribute__((address_space(3))) void*)(&lA[idx1 * 8]), 16, 0, 0);
    __builtin_amdgcn_global_load_lds(
        (const __attribute__((address_space(1))) void*)(gB + (size_t)r0 * C_ + k0 + kc0 * 8),
        (__attribute__((address_space(3))) void*)(&lB[idx0 * 8]), 16, 0, 0);
    __builtin_amdgcn_global_load_lds(
        (const __attribute__((address_space(1))) void*)(gB + (size_t)r1 * C_ + k0 + kc1 * 8),
        (__attribute__((address_space(3))) void*)(&lB[idx1 * 8]), 16, 0, 0);
    __syncthreads();  // drains vmcnt(0): staging visible to all waves

    bf16x8 af[4], bfr[4];
#pragma unroll
    for (int i = 0; i < 4; ++i) {
      af[i] = *(const bf16x8*)&lA[(wrow * 64 + i * 16 + l15) * 32 + quad * 8];
      bfr[i] = *(const bf16x8*)&lB[(wcol * 64 + i * 16 + l15) * 32 + quad * 8];
    }
#pragma unroll
    for (int i = 0; i < 4; ++i)
#pragma unroll
      for (int j = 0; j < 4; ++j)
        acc[i][j] = __builtin_amdgcn_mfma_f32_16x16x32_bf16(af[i], bfr[j], acc[i][j], 0, 0, 0);
    __syncthreads();  // all waves done reading LDS before next stage
  }

  // epilogue: C/D layout col=lane&15, row=quad*4+reg (m89-verified)
#pragma unroll
  for (int j = 0; j < 4; ++j) {
    const int col = nt * 128 + wcol * 64 + j * 16 + l15;
    const float bias = bbase[col];
#pragma unroll
    for (int i = 0; i < 4; ++i) {
#pragma unroll
      for (int r = 0; r < 4; ++r) {
        const int row = mt * 128 + wrow * 64 + i * 16 + quad * 4 + r;
        if (row < T_) out[((size_t)b * T_ + row) * O_ + col] = acc[i][j][r] + bias;
      }
    }
  }
}

extern "C" void kernel_launch(void* const* d_in, const int* in_sizes, int n_in,
                              void* d_out, int out_size, void* d_ws, size_t ws_size,
                              hipStream_t stream) {
  const float* x = (const float*)d_in[0];    // (16,1500,1024)
  const float* w = (const float*)d_in[1];    // (16,8)
  const float* Wb = (const float*)d_in[2];   // (1024,1024)
  const float* bb = (const float*)d_in[3];   // (1024,)
  const float* As = (const float*)d_in[4];   // (8,16,1024)
  const float* Bs = (const float*)d_in[5];   // (8,1024,16)
  float* out = (float*)d_out;                // (16,1500,1024) fp32

  // ws layout: [0, 49.15 MB) x_bf16 ; [49.15, 82.7 MB) merged weights bf16.
  // (tail-tile staging over-read from x_bf16 lands in the wm region - allocated, harmless)
  u16* xb = (u16*)d_ws;
  u16* wmp = xb + (size_t)B_ * T_ * C_;  // 24,576,000 elements

  cvt_x<<<24000, 256, 0, stream>>>((const float4*)x, (ushort4*)xb);
  build_wm<<<4096, 256, 0, stream>>>(w, Wb, As, Bs, wmp);
  gemm_merged<<<dim3(12, 8, 16), 256, 0, stream>>>(xb, wmp, bb, out);
}